// Round 9
// baseline (1036.551 us; speedup 1.0000x reference)
//
#include <hip/hip_runtime.h>
#include <hip/hip_bf16.h>
#include <math.h>

// ---------------- constants (from reference) ----------------
#define F_IN   336
#define HC     200      // H*C
#define Cch    100      // channels per head
#define SLOPE  0.2f
#define SCAN_BS 256

// padded dims for MFMA GEMM
#define NPAD   224      // HC padded to 14*16
#define KP0    352      // F_IN padded to mult of 32
#define KP1    224      // HC padded to mult of 32

using short8   = __attribute__((ext_vector_type(8))) short;
using float4v  = __attribute__((ext_vector_type(4))) float;
using ushort4v = __attribute__((ext_vector_type(4))) unsigned short;
using float2v  = __attribute__((ext_vector_type(2))) float;

// ---------------- bf16 split helpers ----------------
__device__ inline unsigned short rne_bf16(float v) {
    unsigned int u = __float_as_uint(v);
    return (unsigned short)((u + 0x7fffu + ((u >> 16) & 1u)) >> 16);
}
__device__ inline void split_bf(float v, unsigned short& hi, unsigned short& lo) {
    hi = rne_bf16(v);
    float hv = __uint_as_float(((unsigned int)hi) << 16);
    lo = rne_bf16(v - hv);
}

// ---------------- CSR build ----------------
__global__ void init_deg(int* deg, int n) {
    int i = blockIdx.x * 256 + threadIdx.x;
    if (i < n) deg[i] = 1;   // self-loop
}

__global__ void count_deg(const int* __restrict__ dst, int* deg, int e) {
    int i = blockIdx.x * 256 + threadIdx.x;
    if (i < e) atomicAdd(&deg[dst[i]], 1);
}

__global__ void scan_block(const int* __restrict__ deg, int* incl, int* bsums, int n) {
    __shared__ int sm[SCAN_BS];
    int i = blockIdx.x * SCAN_BS + threadIdx.x;
    int v = (i < n) ? deg[i] : 0;
    sm[threadIdx.x] = v;
    __syncthreads();
    for (int off = 1; off < SCAN_BS; off <<= 1) {
        int t = (threadIdx.x >= off) ? sm[threadIdx.x - off] : 0;
        __syncthreads();
        sm[threadIdx.x] += t;
        __syncthreads();
    }
    if (i < n) incl[i] = sm[threadIdx.x];
    if (threadIdx.x == SCAN_BS - 1) bsums[blockIdx.x] = sm[threadIdx.x];
}

__global__ void scan_sums(int* bsums, int nb) {
    __shared__ int sm[SCAN_BS];
    int v = (threadIdx.x < nb) ? bsums[threadIdx.x] : 0;
    sm[threadIdx.x] = v;
    __syncthreads();
    for (int off = 1; off < SCAN_BS; off <<= 1) {
        int t = (threadIdx.x >= off) ? sm[threadIdx.x - off] : 0;
        __syncthreads();
        sm[threadIdx.x] += t;
        __syncthreads();
    }
    if (threadIdx.x < nb) bsums[threadIdx.x] = sm[threadIdx.x] - v;  // exclusive
}

__global__ void scan_final(const int* __restrict__ incl, const int* __restrict__ deg,
                           const int* __restrict__ bsums, int* row_ptr, int* cursor, int n) {
    int i = blockIdx.x * SCAN_BS + threadIdx.x;
    if (i < n) {
        int inc = incl[i] + bsums[i / SCAN_BS];
        int ex  = inc - deg[i];
        row_ptr[i] = ex;
        cursor[i]  = ex;
        if (i == n - 1) row_ptr[n] = inc;
    }
}

__global__ void fill_csr(const int* __restrict__ src, const int* __restrict__ dst,
                         int* cursor, int* col_src, int e, int n) {
    int i = blockIdx.x * 256 + threadIdx.x;
    int te = e + n;
    if (i >= te) return;
    int s, d;
    if (i < e) { s = src[i]; d = dst[i]; }
    else       { s = i - e;  d = i - e; }
    int pos = atomicAdd(&cursor[d], 1);
    col_src[pos] = s;
}

// ---------------- split conversions ----------------
__global__ void conv_x(const float* __restrict__ x, unsigned short* __restrict__ Ah,
                       unsigned short* __restrict__ Al, int n_nodes) {
    const int GPR = KP0 / 4;   // 88 groups per row
    int i = blockIdx.x * 256 + threadIdx.x;
    int tot = n_nodes * GPR;
    if (i >= tot) return;
    int row = i / GPR, g4 = i - row * GPR;
    int col = g4 * 4;
    float4v v = {0.f, 0.f, 0.f, 0.f};
    if (col < F_IN) v = *(const float4v*)(x + (size_t)row * F_IN + col);
    ushort4v hv, lv;
    split_bf(v.x, ((unsigned short*)&hv)[0], ((unsigned short*)&lv)[0]);
    split_bf(v.y, ((unsigned short*)&hv)[1], ((unsigned short*)&lv)[1]);
    split_bf(v.z, ((unsigned short*)&hv)[2], ((unsigned short*)&lv)[2]);
    split_bf(v.w, ((unsigned short*)&hv)[3], ((unsigned short*)&lv)[3]);
    size_t b = (size_t)row * KP0 + col;
    *(ushort4v*)(Ah + b) = hv;
    *(ushort4v*)(Al + b) = lv;
}

__global__ void conv_w(const float* __restrict__ W, unsigned short* __restrict__ Bh,
                       unsigned short* __restrict__ Bl, int K, int Kp) {
    int i = blockIdx.x * 256 + threadIdx.x;
    int tot = NPAD * Kp;
    if (i >= tot) return;
    int n = i / Kp, k = i - n * Kp;
    float v = (n < HC && k < K) ? W[(size_t)k * HC + n] : 0.f;
    unsigned short hi, lo;
    split_bf(v, hi, lo);
    Bh[i] = hi; Bl[i] = lo;
}

// ---------------- split-bf16 MFMA GEMM, small blocks for occupancy ----------------
// R8 lesson: 64x224 blocks (782, ~12 waves/CU) were latency-starved at 10% MFMA
// regardless of LDS vs direct staging. This version: block = 2 waves (128 thr),
// 16 rows x 224 cols, wave = 16x112 (1x7 tiles, acc 28 VGPR), grid 3125,
// no barriers in K-loop, partial unroll to avoid KP0 spill.
template<int KP>
__global__ __launch_bounds__(128, 6) void gemm_direct(
    const unsigned short* __restrict__ Ah, const unsigned short* __restrict__ Al,
    const unsigned short* __restrict__ Bh, const unsigned short* __restrict__ Bl,
    const float* __restrict__ asrc, const float* __restrict__ adst,
    float* __restrict__ h, float* __restrict__ es, float* __restrict__ ed,
    int M)
{
    __shared__ float sc[16][4];    // es0, es1, ed0, ed1 per block row
    int tid  = threadIdx.x;
    int wave = tid >> 6, lane = tid & 63;
    int quad = lane >> 4, l16 = lane & 15;
    int wn = wave * 112;
    int r0 = blockIdx.x * 16;

    if (tid < 64) ((float*)sc)[tid] = 0.f;
    __syncthreads();

    int  arow = r0 + l16;
    bool avld = arow < M;
    size_t aoff = (size_t)(avld ? arow : 0) * KP + quad * 8;
    const unsigned short* pa_h = Ah + aoff;
    const unsigned short* pa_l = Al + aoff;
    const unsigned short* pb_h[7];
    const unsigned short* pb_l[7];
#pragma unroll
    for (int nt = 0; nt < 7; nt++) {
        size_t off = (size_t)(wn + nt * 16 + l16) * KP + quad * 8;
        pb_h[nt] = Bh + off;
        pb_l[nt] = Bl + off;
    }

    float4v acc[7];
#pragma unroll
    for (int nt = 0; nt < 7; nt++)
        acc[nt] = (float4v){0.f, 0.f, 0.f, 0.f};

    const short8 zero8 = {0, 0, 0, 0, 0, 0, 0, 0};
#pragma unroll 2
    for (int k0 = 0; k0 < KP; k0 += 32) {
        short8 a_h = avld ? *(const short8*)(pa_h + k0) : zero8;
        short8 a_l = avld ? *(const short8*)(pa_l + k0) : zero8;
#pragma unroll
        for (int nt = 0; nt < 7; nt++) {
            short8 b_h = *(const short8*)(pb_h[nt] + k0);
            short8 b_l = *(const short8*)(pb_l[nt] + k0);
            acc[nt] = __builtin_amdgcn_mfma_f32_16x16x32_bf16(a_h, b_h, acc[nt], 0, 0, 0);
            acc[nt] = __builtin_amdgcn_mfma_f32_16x16x32_bf16(a_h, b_l, acc[nt], 0, 0, 0);
            acc[nt] = __builtin_amdgcn_mfma_f32_16x16x32_bf16(a_l, b_h, acc[nt], 0, 0, 0);
        }
    }

    // per-lane per-nt score weights (uniform loads, cached)
    float asc[7], adc[7];
    bool  vld[7];
    bool  hd1[7];
#pragma unroll
    for (int nt = 0; nt < 7; nt++) {
        int col = wn + nt * 16 + l16;
        vld[nt] = col < HC;
        hd1[nt] = col >= Cch;
        asc[nt] = vld[nt] ? asrc[col] : 0.f;
        adc[nt] = vld[nt] ? adst[col] : 0.f;
    }

    // epilogue: write h + accumulate score partials
    float p[4][4];
#pragma unroll
    for (int r = 0; r < 4; r++)
#pragma unroll
        for (int t = 0; t < 4; t++) p[r][t] = 0.f;
#pragma unroll
    for (int nt = 0; nt < 7; nt++) {
        int col = wn + nt * 16 + l16;
#pragma unroll
        for (int r = 0; r < 4; r++) {
            float v = acc[nt][r];
            int grow = r0 + quad * 4 + r;
            if (vld[nt] && grow < M) h[(size_t)grow * HC + col] = v;
            float va = v * asc[nt], vd = v * adc[nt];
            p[r][0] += hd1[nt] ? 0.f : va;
            p[r][1] += hd1[nt] ? va  : 0.f;
            p[r][2] += hd1[nt] ? 0.f : vd;
            p[r][3] += hd1[nt] ? vd  : 0.f;
        }
    }
#pragma unroll
    for (int off = 1; off < 16; off <<= 1)
#pragma unroll
        for (int r = 0; r < 4; r++)
#pragma unroll
            for (int t = 0; t < 4; t++)
                p[r][t] += __shfl_xor(p[r][t], off);
    if (l16 == 0) {
        int lrow = quad * 4;
#pragma unroll
        for (int r = 0; r < 4; r++)
#pragma unroll
            for (int t = 0; t < 4; t++)
                atomicAdd(&sc[lrow + r][t], p[r][t]);
    }
    __syncthreads();
    if (tid < 16) {
        int grow = r0 + tid;
        if (grow < M) {
            es[grow * 2 + 0] = sc[tid][0];
            es[grow * 2 + 1] = sc[tid][1];
            ed[grow * 2 + 0] = sc[tid][2];
            ed[grow * 2 + 1] = sc[tid][3];
        }
    }
}

// ---------------- softmax weights per edge (16 lanes per dst node) ----------------
__global__ __launch_bounds__(256) void gat_alpha_par(
    const float* __restrict__ es, const float* __restrict__ ed,
    const int* __restrict__ row_ptr, const int* __restrict__ col_src,
    float* __restrict__ pbuf, float* __restrict__ linv, int n_nodes)
{
    int tid = threadIdx.x;
    int sub = tid >> 4;          // node slot within block (0..15)
    int l   = tid & 15;
    int n = blockIdx.x * 16 + sub;
    if (n >= n_nodes) return;    // whole 16-lane groups drop out together
    int e0 = row_ptr[n], e1 = row_ptr[n + 1];
    float ed0 = ed[n * 2], ed1 = ed[n * 2 + 1];
    float m0 = -INFINITY, m1 = -INFINITY;
    for (int e = e0 + l; e < e1; e += 16) {
        int s = col_src[e];
        float2v q = *(const float2v*)&es[s * 2];
        float s0 = q.x + ed0, s1 = q.y + ed1;
        s0 = s0 > 0.f ? s0 : SLOPE * s0;
        s1 = s1 > 0.f ? s1 : SLOPE * s1;
        m0 = fmaxf(m0, s0); m1 = fmaxf(m1, s1);
        float2v w = {s0, s1};
        *(float2v*)&pbuf[(size_t)e * 2] = w;   // stash raw scores
    }
#pragma unroll
    for (int off = 1; off < 16; off <<= 1) {
        m0 = fmaxf(m0, __shfl_xor(m0, off));
        m1 = fmaxf(m1, __shfl_xor(m1, off));
    }
    float l0 = 0.f, l1 = 0.f;
    for (int e = e0 + l; e < e1; e += 16) {
        float2v w = *(const float2v*)&pbuf[(size_t)e * 2];
        float p0 = __expf(w.x - m0), p1 = __expf(w.y - m1);
        l0 += p0; l1 += p1;
        float2v pp = {p0, p1};
        *(float2v*)&pbuf[(size_t)e * 2] = pp;
    }
#pragma unroll
    for (int off = 1; off < 16; off <<= 1) {
        l0 += __shfl_xor(l0, off);
        l1 += __shfl_xor(l1, off);
    }
    if (l == 0) {
        linv[n * 2]     = 1.f / (l0 + 1e-16f);
        linv[n * 2 + 1] = 1.f / (l1 + 1e-16f);
    }
}

// ---------------- weighted gather (wave per dst node) ----------------
// shfl broadcast in UNIFORM control flow (R5 lesson); 4 independent loads in flight.
// lanes 0..49 each own 4 consecutive channels. lanes 0..24 head0, 25..49 head1.
template<bool WF, bool WB>
__global__ __launch_bounds__(256) void gat_gather(
    const float* __restrict__ h, const float* __restrict__ pbuf, const float* __restrict__ linv,
    const int* __restrict__ row_ptr, const int* __restrict__ col_src,
    const float* __restrict__ bias, float* __restrict__ outF,
    unsigned short* __restrict__ oh, unsigned short* __restrict__ ol, int n_nodes)
{
    int wave = threadIdx.x >> 6, lane = threadIdx.x & 63;
    int n = blockIdx.x * 4 + wave;
    if (n >= n_nodes) return;
    int e0 = row_ptr[n], e1 = row_ptr[n + 1];
    bool act  = lane < 50;
    int  hsel = (lane >= 25) ? 1 : 0;

    float4v a0 = {0.f, 0.f, 0.f, 0.f}, a1 = {0.f, 0.f, 0.f, 0.f};
    float4v a2 = {0.f, 0.f, 0.f, 0.f}, a3 = {0.f, 0.f, 0.f, 0.f};

    for (int cbase = e0; cbase < e1; cbase += 64) {
        int cnt = e1 - cbase; if (cnt > 64) cnt = 64;
        int   sidx = 0;
        float px = 0.f, py = 0.f;
        if (lane < cnt) {
            sidx = col_src[cbase + lane];
            float2v pp = *(const float2v*)&pbuf[(size_t)(cbase + lane) * 2];
            px = pp.x; py = pp.y;
        }
        int j = 0;
        for (; j + 4 <= cnt; j += 4) {
            int s0 = __shfl(sidx, j + 0), s1 = __shfl(sidx, j + 1);
            int s2 = __shfl(sidx, j + 2), s3 = __shfl(sidx, j + 3);
            float x0 = __shfl(px, j + 0), y0 = __shfl(py, j + 0);
            float x1 = __shfl(px, j + 1), y1 = __shfl(py, j + 1);
            float x2 = __shfl(px, j + 2), y2 = __shfl(py, j + 2);
            float x3 = __shfl(px, j + 3), y3 = __shfl(py, j + 3);
            float p0 = hsel ? y0 : x0;
            float p1 = hsel ? y1 : x1;
            float p2 = hsel ? y2 : x2;
            float p3 = hsel ? y3 : x3;
            if (act) {
                float4v v0 = *(const float4v*)(h + (size_t)s0 * HC + lane * 4);
                float4v v1 = *(const float4v*)(h + (size_t)s1 * HC + lane * 4);
                float4v v2 = *(const float4v*)(h + (size_t)s2 * HC + lane * 4);
                float4v v3 = *(const float4v*)(h + (size_t)s3 * HC + lane * 4);
                a0.x += p0 * v0.x; a0.y += p0 * v0.y; a0.z += p0 * v0.z; a0.w += p0 * v0.w;
                a1.x += p1 * v1.x; a1.y += p1 * v1.y; a1.z += p1 * v1.z; a1.w += p1 * v1.w;
                a2.x += p2 * v2.x; a2.y += p2 * v2.y; a2.z += p2 * v2.z; a2.w += p2 * v2.w;
                a3.x += p3 * v3.x; a3.y += p3 * v3.y; a3.z += p3 * v3.z; a3.w += p3 * v3.w;
            }
        }
        for (; j < cnt; j++) {
            int s0 = __shfl(sidx, j);
            float x0 = __shfl(px, j), y0 = __shfl(py, j);
            float p0 = hsel ? y0 : x0;
            if (act) {
                float4v v0 = *(const float4v*)(h + (size_t)s0 * HC + lane * 4);
                a0.x += p0 * v0.x; a0.y += p0 * v0.y; a0.z += p0 * v0.z; a0.w += p0 * v0.w;
            }
        }
    }
    float4v acc;
    acc.x = (a0.x + a1.x) + (a2.x + a3.x);
    acc.y = (a0.y + a1.y) + (a2.y + a3.y);
    acc.z = (a0.z + a1.z) + (a2.z + a3.z);
    acc.w = (a0.w + a1.w) + (a2.w + a3.w);

    float li = linv[n * 2 + hsel];
    if (act) {
        float4v bb = *(const float4v*)(bias + lane * 4);
        float4v r;
        r.x = fmaxf(acc.x * li + bb.x, 0.f);
        r.y = fmaxf(acc.y * li + bb.y, 0.f);
        r.z = fmaxf(acc.z * li + bb.z, 0.f);
        r.w = fmaxf(acc.w * li + bb.w, 0.f);
        if (WF) {
            __builtin_nontemporal_store(r, (float4v*)(outF + (size_t)n * HC + lane * 4));
        }
        if (WB) {
            ushort4v hv, lv;
            split_bf(r.x, ((unsigned short*)&hv)[0], ((unsigned short*)&lv)[0]);
            split_bf(r.y, ((unsigned short*)&hv)[1], ((unsigned short*)&lv)[1]);
            split_bf(r.z, ((unsigned short*)&hv)[2], ((unsigned short*)&lv)[2]);
            split_bf(r.w, ((unsigned short*)&hv)[3], ((unsigned short*)&lv)[3]);
            size_t b = (size_t)n * NPAD + lane * 4;
            __builtin_nontemporal_store(hv, (ushort4v*)(oh + b));
            __builtin_nontemporal_store(lv, (ushort4v*)(ol + b));
        }
    } else if (WB && lane < 56) {   // zero pad cols 200..223
        ushort4v z = {0, 0, 0, 0};
        size_t b = (size_t)n * NPAD + lane * 4;
        __builtin_nontemporal_store(z, (ushort4v*)(oh + b));
        __builtin_nontemporal_store(z, (ushort4v*)(ol + b));
    }
}

// ---------------- pooling (node-parallel, atomic partials) ----------------
__global__ void pool_zero(float* pool, int tot) {
    int i = blockIdx.x * 256 + threadIdx.x;
    if (i < tot) pool[i] = 0.f;
}

__global__ __launch_bounds__(256) void pool_part(
    const float* __restrict__ x, const int* __restrict__ batch,
    float* __restrict__ pool, int n_nodes)
{
    int wave = threadIdx.x >> 6, lane = threadIdx.x & 63;
    int base = (blockIdx.x * 4 + wave) * 16;
    if (base >= n_nodes) return;
    bool act = lane < 50;
    int end = base + 16; if (end > n_nodes) end = n_nodes;
    float4v acc = {0.f, 0.f, 0.f, 0.f};
    int curg = batch[base];
    for (int n = base; n < end; n++) {
        int g = batch[n];
        if (g != curg) {
            if (act) {
                float* pp = pool + (size_t)curg * HC + lane * 4;
                atomicAdd(pp + 0, acc.x); atomicAdd(pp + 1, acc.y);
                atomicAdd(pp + 2, acc.z); atomicAdd(pp + 3, acc.w);
            }
            acc = (float4v){0.f, 0.f, 0.f, 0.f};
            curg = g;
        }
        if (act) {
            float4v v = *(const float4v*)(x + (size_t)n * HC + lane * 4);
            acc.x += v.x; acc.y += v.y; acc.z += v.z; acc.w += v.w;
        }
    }
    if (act) {
        float* pp = pool + (size_t)curg * HC + lane * 4;
        atomicAdd(pp + 0, acc.x); atomicAdd(pp + 1, acc.y);
        atomicAdd(pp + 2, acc.z); atomicAdd(pp + 3, acc.w);
    }
}

__global__ void pool_div(float* pool, const int* __restrict__ gstart, int g_count) {
    int i = blockIdx.x * 256 + threadIdx.x;
    if (i >= g_count * HC) return;
    int g = i / HC;
    float cnt = (float)(gstart[g + 1] - gstart[g]);
    pool[i] /= fmaxf(cnt, 1.f);
}

// ---------------- graph boundaries (batch sorted) ----------------
__global__ void graph_bounds(const int* __restrict__ batch, int* gstart, int n, int g) {
    int i = blockIdx.x * 256 + threadIdx.x;
    if (i >= n) return;
    int b = batch[i];
    int bp = (i == 0) ? -1 : batch[i - 1];
    for (int q = bp + 1; q <= b; q++) gstart[q] = i;
    if (i == n - 1) for (int q = b + 1; q <= g; q++) gstart[q] = n;
}

// ---------------- small MLP layers (block per row) ----------------
template<int KIN, int KOUT, bool RELU>
__global__ __launch_bounds__(128) void mlp(
    const float* __restrict__ in, const float* __restrict__ W, const float* __restrict__ b,
    float* __restrict__ out)
{
    __shared__ float xi[KIN];
    int g = blockIdx.x;
    for (int k = threadIdx.x; k < KIN; k += blockDim.x) xi[k] = in[g * KIN + k];
    __syncthreads();
    int j = threadIdx.x;
    if (j < KOUT) {
        float s = b[j];
        for (int k = 0; k < KIN; k++) s = fmaf(xi[k], W[k * KOUT + j], s);
        if (RELU) s = fmaxf(s, 0.f);
        out[g * KOUT + j] = s;
    }
}

// ---------------- launch ----------------
extern "C" void kernel_launch(void* const* d_in, const int* in_sizes, int n_in,
                              void* d_out, int out_size, void* d_ws, size_t ws_size,
                              hipStream_t stream) {
    const float* x     = (const float*)d_in[0];
    const int*   ei    = (const int*)d_in[1];
    const int*   batch = (const int*)d_in[2];
    const float *W[5], *asrc[5], *adst[5], *bc[5];
    for (int i = 0; i < 5; i++) {
        W[i]    = (const float*)d_in[3 + i * 4];
        asrc[i] = (const float*)d_in[4 + i * 4];
        adst[i] = (const float*)d_in[5 + i * 4];
        bc[i]   = (const float*)d_in[6 + i * 4];
    }
    const float* lw1 = (const float*)d_in[23];
    const float* lb1 = (const float*)d_in[24];
    const float* lw2 = (const float*)d_in[25];
    const float* lb2 = (const float*)d_in[26];
    const float* lw3 = (const float*)d_in[27];
    const float* lb3 = (const float*)d_in[28];
    float* out = (float*)d_out;

    const int N  = in_sizes[0] / F_IN;
    const int E  = in_sizes[1] / 2;
    const int G  = out_size / 29;
    const int TE = E + N;
    const int* esrc = ei;
    const int* edst = ei + E;

    // workspace carve
    char* p = (char*)d_ws;
    auto carve = [&](size_t bytes) { void* r = (void*)p; p += ((bytes + 255) / 256) * 256; return r; };
    float*          hbuf = (float*)carve((size_t)N * HC * 4);          // GEMM out h (fp32)
    unsigned short* Ah   = (unsigned short*)carve((size_t)N * KP0 * 2);
    unsigned short* Al   = (unsigned short*)carve((size_t)N * KP0 * 2);
    float*          outF = (float*)Ah;  // aliases Ah/Al (dead by the time L5 gather writes)
    unsigned short* Wth  = (unsigned short*)carve((size_t)NPAD * KP0 * 2);
    unsigned short* Wtl  = (unsigned short*)carve((size_t)NPAD * KP0 * 2);
    float* es_     = (float*)carve((size_t)N * 2 * 4);
    float* ed_     = (float*)carve((size_t)N * 2 * 4);
    float* pbuf    = (float*)carve((size_t)TE * 2 * 4);
    float* linv    = (float*)carve((size_t)N * 2 * 4);
    int*   deg     = (int*)carve((size_t)N * 4);
    int*   incl    = (int*)carve((size_t)N * 4);
    int*   bsums   = (int*)carve(SCAN_BS * 4);
    int*   row_ptr = (int*)carve((size_t)(N + 1) * 4);
    int*   cursor  = (int*)carve((size_t)N * 4);
    int*   col_src = (int*)carve((size_t)TE * 4);
    int*   gstart  = (int*)carve((size_t)(G + 1) * 4);
    float* pool    = (float*)carve((size_t)G * HC * 4);
    float* t1      = (float*)carve((size_t)G * 100 * 4);
    float* t2      = (float*)carve((size_t)G * 100 * 4);

    const int nBlkN   = (N + 255) / 256;
    const int nBlkE   = (E + 255) / 256;
    const int nBlkTE  = (TE + 255) / 256;
    const int nScanB  = (N + SCAN_BS - 1) / SCAN_BS;
    const int nWaveB  = (N + 3) / 4;
    const int nGemmB  = (N + 15) / 16;   // 16 rows per block (2-wave blocks)
    const int nPoolB  = (N + 63) / 64;
    const int nAlphaB = (N + 15) / 16;

    // ---- CSR build ----
    init_deg<<<nBlkN, 256, 0, stream>>>(deg, N);
    count_deg<<<nBlkE, 256, 0, stream>>>(edst, deg, E);
    scan_block<<<nScanB, SCAN_BS, 0, stream>>>(deg, incl, bsums, N);
    scan_sums<<<1, SCAN_BS, 0, stream>>>(bsums, nScanB);
    scan_final<<<nScanB, SCAN_BS, 0, stream>>>(incl, deg, bsums, row_ptr, cursor, N);
    fill_csr<<<nBlkTE, 256, 0, stream>>>(esrc, edst, cursor, col_src, E, N);

    // ---- input split ----
    conv_x<<<(N * (KP0 / 4) + 255) / 256, 256, 0, stream>>>(x, Ah, Al, N);

    // ---- 5 GAT layers ----
    for (int L = 0; L < 5; L++) {
        int K  = (L == 0) ? F_IN : HC;
        int Kp = (L == 0) ? KP0 : KP1;
        conv_w<<<(NPAD * Kp + 255) / 256, 256, 0, stream>>>(W[L], Wth, Wtl, K, Kp);
        if (L == 0)
            gemm_direct<KP0><<<nGemmB, 128, 0, stream>>>(Ah, Al, Wth, Wtl, asrc[L], adst[L],
                                                         hbuf, es_, ed_, N);
        else
            gemm_direct<KP1><<<nGemmB, 128, 0, stream>>>(Ah, Al, Wth, Wtl, asrc[L], adst[L],
                                                         hbuf, es_, ed_, N);
        gat_alpha_par<<<nAlphaB, 256, 0, stream>>>(es_, ed_, row_ptr, col_src, pbuf, linv, N);
        if (L < 4)
            gat_gather<false, true><<<nWaveB, 256, 0, stream>>>(hbuf, pbuf, linv, row_ptr, col_src,
                                                                bc[L], nullptr, Ah, Al, N);
        else
            gat_gather<true, false><<<nWaveB, 256, 0, stream>>>(hbuf, pbuf, linv, row_ptr, col_src,
                                                                bc[L], outF, nullptr, nullptr, N);
    }

    // ---- pooling ----
    graph_bounds<<<nBlkN, 256, 0, stream>>>(batch, gstart, N, G);
    pool_zero<<<(G * HC + 255) / 256, 256, 0, stream>>>(pool, G * HC);
    pool_part<<<nPoolB, 256, 0, stream>>>(outF, batch, pool, N);
    pool_div<<<(G * HC + 255) / 256, 256, 0, stream>>>(pool, gstart, G);

    // ---- MLP head ----
    mlp<200, 100, true ><<<G, 128, 0, stream>>>(pool, lw1, lb1, t1);
    mlp<100, 100, true ><<<G, 128, 0, stream>>>(t1, lw2, lb2, t2);
    mlp<100, 29,  false><<<G, 128, 0, stream>>>(t2, lw3, lb3, out);
}

// Round 10
// 809.782 us; speedup vs baseline: 1.2800x; 1.2800x over previous
//
#include <hip/hip_runtime.h>
#include <hip/hip_bf16.h>
#include <math.h>

// ---------------- constants (from reference) ----------------
#define F_IN   336
#define HC     200      // H*C
#define Cch    100      // channels per head
#define SLOPE  0.2f
#define SCAN_BS 256

// padded dims for MFMA GEMM
#define NPAD   224      // HC padded to 14*16
#define KP0    352      // F_IN padded to mult of 32
#define KP1    224      // HC padded to mult of 32

using short8   = __attribute__((ext_vector_type(8))) short;
using float4v  = __attribute__((ext_vector_type(4))) float;
using ushort4v = __attribute__((ext_vector_type(4))) unsigned short;
using float2v  = __attribute__((ext_vector_type(2))) float;

// ---------------- bf16 split helpers ----------------
__device__ inline unsigned short rne_bf16(float v) {
    unsigned int u = __float_as_uint(v);
    return (unsigned short)((u + 0x7fffu + ((u >> 16) & 1u)) >> 16);
}
__device__ inline void split_bf(float v, unsigned short& hi, unsigned short& lo) {
    hi = rne_bf16(v);
    float hv = __uint_as_float(((unsigned int)hi) << 16);
    lo = rne_bf16(v - hv);
}

// ---------------- CSR build ----------------
__global__ void init_deg(int* deg, int n) {
    int i = blockIdx.x * 256 + threadIdx.x;
    if (i < n) deg[i] = 1;   // self-loop
}

__global__ void count_deg(const int* __restrict__ dst, int* deg, int e) {
    int i = blockIdx.x * 256 + threadIdx.x;
    if (i < e) atomicAdd(&deg[dst[i]], 1);
}

__global__ void scan_block(const int* __restrict__ deg, int* incl, int* bsums, int n) {
    __shared__ int sm[SCAN_BS];
    int i = blockIdx.x * SCAN_BS + threadIdx.x;
    int v = (i < n) ? deg[i] : 0;
    sm[threadIdx.x] = v;
    __syncthreads();
    for (int off = 1; off < SCAN_BS; off <<= 1) {
        int t = (threadIdx.x >= off) ? sm[threadIdx.x - off] : 0;
        __syncthreads();
        sm[threadIdx.x] += t;
        __syncthreads();
    }
    if (i < n) incl[i] = sm[threadIdx.x];
    if (threadIdx.x == SCAN_BS - 1) bsums[blockIdx.x] = sm[threadIdx.x];
}

__global__ void scan_sums(int* bsums, int nb) {
    __shared__ int sm[SCAN_BS];
    int v = (threadIdx.x < nb) ? bsums[threadIdx.x] : 0;
    sm[threadIdx.x] = v;
    __syncthreads();
    for (int off = 1; off < SCAN_BS; off <<= 1) {
        int t = (threadIdx.x >= off) ? sm[threadIdx.x - off] : 0;
        __syncthreads();
        sm[threadIdx.x] += t;
        __syncthreads();
    }
    if (threadIdx.x < nb) bsums[threadIdx.x] = sm[threadIdx.x] - v;  // exclusive
}

__global__ void scan_final(const int* __restrict__ incl, const int* __restrict__ deg,
                           const int* __restrict__ bsums, int* row_ptr, int* cursor, int n) {
    int i = blockIdx.x * SCAN_BS + threadIdx.x;
    if (i < n) {
        int inc = incl[i] + bsums[i / SCAN_BS];
        int ex  = inc - deg[i];
        row_ptr[i] = ex;
        cursor[i]  = ex;
        if (i == n - 1) row_ptr[n] = inc;
    }
}

__global__ void fill_csr(const int* __restrict__ src, const int* __restrict__ dst,
                         int* cursor, int* col_src, int e, int n) {
    int i = blockIdx.x * 256 + threadIdx.x;
    int te = e + n;
    if (i >= te) return;
    int s, d;
    if (i < e) { s = src[i]; d = dst[i]; }
    else       { s = i - e;  d = i - e; }
    int pos = atomicAdd(&cursor[d], 1);
    col_src[pos] = s;
}

// ---------------- split conversions ----------------
__global__ void conv_x(const float* __restrict__ x, unsigned short* __restrict__ Ah,
                       unsigned short* __restrict__ Al, int n_nodes) {
    const int GPR = KP0 / 4;   // 88 groups per row
    int i = blockIdx.x * 256 + threadIdx.x;
    int tot = n_nodes * GPR;
    if (i >= tot) return;
    int row = i / GPR, g4 = i - row * GPR;
    int col = g4 * 4;
    float4v v = {0.f, 0.f, 0.f, 0.f};
    if (col < F_IN) v = *(const float4v*)(x + (size_t)row * F_IN + col);
    ushort4v hv, lv;
    split_bf(v.x, ((unsigned short*)&hv)[0], ((unsigned short*)&lv)[0]);
    split_bf(v.y, ((unsigned short*)&hv)[1], ((unsigned short*)&lv)[1]);
    split_bf(v.z, ((unsigned short*)&hv)[2], ((unsigned short*)&lv)[2]);
    split_bf(v.w, ((unsigned short*)&hv)[3], ((unsigned short*)&lv)[3]);
    size_t b = (size_t)row * KP0 + col;
    *(ushort4v*)(Ah + b) = hv;
    *(ushort4v*)(Al + b) = lv;
}

__global__ void conv_w(const float* __restrict__ W, unsigned short* __restrict__ Bh,
                       unsigned short* __restrict__ Bl, int K, int Kp) {
    int i = blockIdx.x * 256 + threadIdx.x;
    int tot = NPAD * Kp;
    if (i >= tot) return;
    int n = i / Kp, k = i - n * Kp;
    float v = (n < HC && k < K) ? W[(size_t)k * HC + n] : 0.f;
    unsigned short hi, lo;
    split_bf(v, hi, lo);
    Bh[i] = hi; Bl[i] = lo;
}

// ---------------- split-bf16 MFMA GEMM + fused attention scores (R7 version) ----------------
// h[M,200] = A[M,Kp] @ Wt^T ; es/ed[n][head] = sum_c h[n][c]*a{s,d}[c]
// R8/R9 lesson: direct-to-reg and small-block variants both land at the same
// ~10% MfmaUtil plateau but slower overall; this LDS-staged 64x224 block is
// the empirical best (77us). Do not re-speculate without new counter evidence.
#define LDK 40   // LDS k-stride (32 + 8 pad -> 2-way bank conflicts only, free per m136)
__global__ __launch_bounds__(256, 2) void gemm_split(
    const unsigned short* __restrict__ Ah, const unsigned short* __restrict__ Al,
    const unsigned short* __restrict__ Bh, const unsigned short* __restrict__ Bl,
    const float* __restrict__ asrc, const float* __restrict__ adst,
    float* __restrict__ h, float* __restrict__ es, float* __restrict__ ed,
    int M, int Kp)
{
    __shared__ unsigned short As[2][64][LDK];
    __shared__ unsigned short Bs[2][NPAD][LDK];
    __shared__ float sc[64][4];    // es0, es1, ed0, ed1 per block row
    int tid  = threadIdx.x;
    int wave = tid >> 6, lane = tid & 63;
    int quad = lane >> 4, l16 = lane & 15;
    int wm = (wave >> 1) * 32;
    int wn = (wave & 1) * 112;
    int r0 = blockIdx.x * 64;

    ((float*)sc)[tid] = 0.f;   // 64*4 == 256 — one element per thread

    float4v acc[2][7];
#pragma unroll
    for (int mt = 0; mt < 2; mt++)
#pragma unroll
        for (int nt = 0; nt < 7; nt++)
            acc[mt][nt] = (float4v){0.f, 0.f, 0.f, 0.f};

    for (int k0 = 0; k0 < Kp; k0 += 32) {
#pragma unroll
        for (int i = 0; i < 2; i++) {
            int c = tid + 256 * i;
            int s = c >> 8;
            int cc = c & 255;
            int row = cc >> 2, kc = (cc & 3) * 8;
            const unsigned short* g = s ? Al : Ah;
            uint4 v = make_uint4(0u, 0u, 0u, 0u);
            int gr = r0 + row;
            if (gr < M) v = *(const uint4*)(g + (size_t)gr * Kp + k0 + kc);
            *(uint4*)&As[s][row][kc] = v;
        }
#pragma unroll
        for (int i = 0; i < 7; i++) {
            int c = tid + 256 * i;
            int s = (c >= 896) ? 1 : 0;
            int cc = c - s * 896;
            int row = cc >> 2, kc = (cc & 3) * 8;
            const unsigned short* g = s ? Bl : Bh;
            *(uint4*)&Bs[s][row][kc] = *(const uint4*)(g + (size_t)row * Kp + k0 + kc);
        }
        __syncthreads();

        short8 a_h[2], a_l[2];
#pragma unroll
        for (int mt = 0; mt < 2; mt++) {
            a_h[mt] = *(const short8*)&As[0][wm + mt * 16 + l16][quad * 8];
            a_l[mt] = *(const short8*)&As[1][wm + mt * 16 + l16][quad * 8];
        }
#pragma unroll
        for (int nt = 0; nt < 7; nt++) {
            short8 b_h = *(const short8*)&Bs[0][wn + nt * 16 + l16][quad * 8];
            short8 b_l = *(const short8*)&Bs[1][wn + nt * 16 + l16][quad * 8];
#pragma unroll
            for (int mt = 0; mt < 2; mt++) {
                acc[mt][nt] = __builtin_amdgcn_mfma_f32_16x16x32_bf16(a_h[mt], b_h, acc[mt][nt], 0, 0, 0);
                acc[mt][nt] = __builtin_amdgcn_mfma_f32_16x16x32_bf16(a_h[mt], b_l, acc[mt][nt], 0, 0, 0);
                acc[mt][nt] = __builtin_amdgcn_mfma_f32_16x16x32_bf16(a_l[mt], b_h, acc[mt][nt], 0, 0, 0);
            }
        }
        __syncthreads();
    }

    // per-lane per-nt score weights (uniform loads, cached)
    float asc[7], adc[7];
    bool  vld[7];
    bool  hd1[7];
#pragma unroll
    for (int nt = 0; nt < 7; nt++) {
        int col = wn + nt * 16 + l16;
        vld[nt] = col < HC;
        hd1[nt] = col >= Cch;
        asc[nt] = vld[nt] ? asrc[col] : 0.f;
        adc[nt] = vld[nt] ? adst[col] : 0.f;
    }

    // epilogue: write h + accumulate score partials
#pragma unroll
    for (int mt = 0; mt < 2; mt++) {
        float p[4][4];
#pragma unroll
        for (int r = 0; r < 4; r++)
#pragma unroll
            for (int t = 0; t < 4; t++) p[r][t] = 0.f;
#pragma unroll
        for (int nt = 0; nt < 7; nt++) {
            int col = wn + nt * 16 + l16;
#pragma unroll
            for (int r = 0; r < 4; r++) {
                float v = acc[mt][nt][r];
                int grow = r0 + wm + mt * 16 + quad * 4 + r;
                if (vld[nt] && grow < M) h[(size_t)grow * HC + col] = v;
                float va = v * asc[nt], vd = v * adc[nt];
                p[r][0] += hd1[nt] ? 0.f : va;
                p[r][1] += hd1[nt] ? va  : 0.f;
                p[r][2] += hd1[nt] ? 0.f : vd;
                p[r][3] += hd1[nt] ? vd  : 0.f;
            }
        }
#pragma unroll
        for (int off = 1; off < 16; off <<= 1)
#pragma unroll
            for (int r = 0; r < 4; r++)
#pragma unroll
                for (int t = 0; t < 4; t++)
                    p[r][t] += __shfl_xor(p[r][t], off);
        if (l16 == 0) {
            int lrow = wm + mt * 16 + quad * 4;
#pragma unroll
            for (int r = 0; r < 4; r++)
#pragma unroll
                for (int t = 0; t < 4; t++)
                    atomicAdd(&sc[lrow + r][t], p[r][t]);
        }
    }
    __syncthreads();
    if (tid < 64) {
        int grow = r0 + tid;
        if (grow < M) {
            es[grow * 2 + 0] = sc[tid][0];
            es[grow * 2 + 1] = sc[tid][1];
            ed[grow * 2 + 0] = sc[tid][2];
            ed[grow * 2 + 1] = sc[tid][3];
        }
    }
}

// ---------------- fused softmax + weighted gather (wave per dst node) ----------------
// out = (sum_e p_e * h[src_e]) / (l + 1e-16) with p unnormalized -> alpha kernel
// and pbuf/linv round-trip eliminated. Pass A: wave-max of scores (12 B/edge).
// Pass B: p=exp(s-m), accumulate l, shfl-broadcast gather (R5 lesson: shfls in
// uniform control flow only).
template<bool WF, bool WB>
__global__ __launch_bounds__(256) void gat_gather(
    const float* __restrict__ h, const float* __restrict__ es, const float* __restrict__ ed,
    const int* __restrict__ row_ptr, const int* __restrict__ col_src,
    const float* __restrict__ bias, float* __restrict__ outF,
    unsigned short* __restrict__ oh, unsigned short* __restrict__ ol, int n_nodes)
{
    int wave = threadIdx.x >> 6, lane = threadIdx.x & 63;
    int n = blockIdx.x * 4 + wave;
    if (n >= n_nodes) return;
    int e0 = row_ptr[n], e1 = row_ptr[n + 1];
    bool act  = lane < 50;
    int  hsel = (lane >= 25) ? 1 : 0;
    float ed0 = ed[n * 2], ed1 = ed[n * 2 + 1];

    // ---- pass A: per-head max over incoming edges ----
    float m0 = -INFINITY, m1 = -INFINITY;
    for (int cbase = e0; cbase < e1; cbase += 64) {
        int cnt = e1 - cbase; if (cnt > 64) cnt = 64;
        if (lane < cnt) {
            int s = col_src[cbase + lane];
            float2v q = *(const float2v*)&es[s * 2];
            float s0 = q.x + ed0, s1 = q.y + ed1;
            s0 = s0 > 0.f ? s0 : SLOPE * s0;
            s1 = s1 > 0.f ? s1 : SLOPE * s1;
            m0 = fmaxf(m0, s0); m1 = fmaxf(m1, s1);
        }
    }
#pragma unroll
    for (int off = 1; off < 64; off <<= 1) {
        m0 = fmaxf(m0, __shfl_xor(m0, off));
        m1 = fmaxf(m1, __shfl_xor(m1, off));
    }

    // ---- pass B: p = exp(s-m), accumulate l, gather with unnormalized p ----
    float l0 = 0.f, l1 = 0.f;
    float4v a0 = {0.f, 0.f, 0.f, 0.f}, a1 = {0.f, 0.f, 0.f, 0.f};
    float4v a2 = {0.f, 0.f, 0.f, 0.f}, a3 = {0.f, 0.f, 0.f, 0.f};

    for (int cbase = e0; cbase < e1; cbase += 64) {
        int cnt = e1 - cbase; if (cnt > 64) cnt = 64;
        int   sidx = 0;
        float px = 0.f, py = 0.f;
        if (lane < cnt) {
            sidx = col_src[cbase + lane];
            float2v q = *(const float2v*)&es[sidx * 2];
            float s0 = q.x + ed0, s1 = q.y + ed1;
            s0 = s0 > 0.f ? s0 : SLOPE * s0;
            s1 = s1 > 0.f ? s1 : SLOPE * s1;
            px = __expf(s0 - m0);
            py = __expf(s1 - m1);
            l0 += px; l1 += py;
        }
        int j = 0;
        for (; j + 4 <= cnt; j += 4) {
            int s0 = __shfl(sidx, j + 0), s1 = __shfl(sidx, j + 1);
            int s2 = __shfl(sidx, j + 2), s3 = __shfl(sidx, j + 3);
            float x0 = __shfl(px, j + 0), y0 = __shfl(py, j + 0);
            float x1 = __shfl(px, j + 1), y1 = __shfl(py, j + 1);
            float x2 = __shfl(px, j + 2), y2 = __shfl(py, j + 2);
            float x3 = __shfl(px, j + 3), y3 = __shfl(py, j + 3);
            float p0 = hsel ? y0 : x0;
            float p1 = hsel ? y1 : x1;
            float p2 = hsel ? y2 : x2;
            float p3 = hsel ? y3 : x3;
            if (act) {
                float4v v0 = *(const float4v*)(h + (size_t)s0 * HC + lane * 4);
                float4v v1 = *(const float4v*)(h + (size_t)s1 * HC + lane * 4);
                float4v v2 = *(const float4v*)(h + (size_t)s2 * HC + lane * 4);
                float4v v3 = *(const float4v*)(h + (size_t)s3 * HC + lane * 4);
                a0.x += p0 * v0.x; a0.y += p0 * v0.y; a0.z += p0 * v0.z; a0.w += p0 * v0.w;
                a1.x += p1 * v1.x; a1.y += p1 * v1.y; a1.z += p1 * v1.z; a1.w += p1 * v1.w;
                a2.x += p2 * v2.x; a2.y += p2 * v2.y; a2.z += p2 * v2.z; a2.w += p2 * v2.w;
                a3.x += p3 * v3.x; a3.y += p3 * v3.y; a3.z += p3 * v3.z; a3.w += p3 * v3.w;
            }
        }
        for (; j < cnt; j++) {
            int s0 = __shfl(sidx, j);
            float x0 = __shfl(px, j), y0 = __shfl(py, j);
            float p0 = hsel ? y0 : x0;
            if (act) {
                float4v v0 = *(const float4v*)(h + (size_t)s0 * HC + lane * 4);
                a0.x += p0 * v0.x; a0.y += p0 * v0.y; a0.z += p0 * v0.z; a0.w += p0 * v0.w;
            }
        }
    }
#pragma unroll
    for (int off = 1; off < 64; off <<= 1) {
        l0 += __shfl_xor(l0, off);
        l1 += __shfl_xor(l1, off);
    }

    float4v acc;
    acc.x = (a0.x + a1.x) + (a2.x + a3.x);
    acc.y = (a0.y + a1.y) + (a2.y + a3.y);
    acc.z = (a0.z + a1.z) + (a2.z + a3.z);
    acc.w = (a0.w + a1.w) + (a2.w + a3.w);

    float li = 1.f / ((hsel ? l1 : l0) + 1e-16f);
    if (act) {
        float4v bb = *(const float4v*)(bias + lane * 4);
        float4v r;
        r.x = fmaxf(acc.x * li + bb.x, 0.f);
        r.y = fmaxf(acc.y * li + bb.y, 0.f);
        r.z = fmaxf(acc.z * li + bb.z, 0.f);
        r.w = fmaxf(acc.w * li + bb.w, 0.f);
        if (WF) {
            __builtin_nontemporal_store(r, (float4v*)(outF + (size_t)n * HC + lane * 4));
        }
        if (WB) {
            ushort4v hv, lv;
            split_bf(r.x, ((unsigned short*)&hv)[0], ((unsigned short*)&lv)[0]);
            split_bf(r.y, ((unsigned short*)&hv)[1], ((unsigned short*)&lv)[1]);
            split_bf(r.z, ((unsigned short*)&hv)[2], ((unsigned short*)&lv)[2]);
            split_bf(r.w, ((unsigned short*)&hv)[3], ((unsigned short*)&lv)[3]);
            size_t b = (size_t)n * NPAD + lane * 4;
            __builtin_nontemporal_store(hv, (ushort4v*)(oh + b));
            __builtin_nontemporal_store(lv, (ushort4v*)(ol + b));
        }
    } else if (WB && lane < 56) {   // zero pad cols 200..223
        ushort4v z = {0, 0, 0, 0};
        size_t b = (size_t)n * NPAD + lane * 4;
        __builtin_nontemporal_store(z, (ushort4v*)(oh + b));
        __builtin_nontemporal_store(z, (ushort4v*)(ol + b));
    }
}

// ---------------- pooling (node-parallel, atomic partials) ----------------
__global__ void pool_zero(float* pool, int tot) {
    int i = blockIdx.x * 256 + threadIdx.x;
    if (i < tot) pool[i] = 0.f;
}

__global__ __launch_bounds__(256) void pool_part(
    const float* __restrict__ x, const int* __restrict__ batch,
    float* __restrict__ pool, int n_nodes)
{
    int wave = threadIdx.x >> 6, lane = threadIdx.x & 63;
    int base = (blockIdx.x * 4 + wave) * 16;
    if (base >= n_nodes) return;
    bool act = lane < 50;
    int end = base + 16; if (end > n_nodes) end = n_nodes;
    float4v acc = {0.f, 0.f, 0.f, 0.f};
    int curg = batch[base];
    for (int n = base; n < end; n++) {
        int g = batch[n];
        if (g != curg) {
            if (act) {
                float* pp = pool + (size_t)curg * HC + lane * 4;
                atomicAdd(pp + 0, acc.x); atomicAdd(pp + 1, acc.y);
                atomicAdd(pp + 2, acc.z); atomicAdd(pp + 3, acc.w);
            }
            acc = (float4v){0.f, 0.f, 0.f, 0.f};
            curg = g;
        }
        if (act) {
            float4v v = *(const float4v*)(x + (size_t)n * HC + lane * 4);
            acc.x += v.x; acc.y += v.y; acc.z += v.z; acc.w += v.w;
        }
    }
    if (act) {
        float* pp = pool + (size_t)curg * HC + lane * 4;
        atomicAdd(pp + 0, acc.x); atomicAdd(pp + 1, acc.y);
        atomicAdd(pp + 2, acc.z); atomicAdd(pp + 3, acc.w);
    }
}

__global__ void pool_div(float* pool, const int* __restrict__ gstart, int g_count) {
    int i = blockIdx.x * 256 + threadIdx.x;
    if (i >= g_count * HC) return;
    int g = i / HC;
    float cnt = (float)(gstart[g + 1] - gstart[g]);
    pool[i] /= fmaxf(cnt, 1.f);
}

// ---------------- graph boundaries (batch sorted) ----------------
__global__ void graph_bounds(const int* __restrict__ batch, int* gstart, int n, int g) {
    int i = blockIdx.x * 256 + threadIdx.x;
    if (i >= n) return;
    int b = batch[i];
    int bp = (i == 0) ? -1 : batch[i - 1];
    for (int q = bp + 1; q <= b; q++) gstart[q] = i;
    if (i == n - 1) for (int q = b + 1; q <= g; q++) gstart[q] = n;
}

// ---------------- small MLP layers (block per row) ----------------
template<int KIN, int KOUT, bool RELU>
__global__ __launch_bounds__(128) void mlp(
    const float* __restrict__ in, const float* __restrict__ W, const float* __restrict__ b,
    float* __restrict__ out)
{
    __shared__ float xi[KIN];
    int g = blockIdx.x;
    for (int k = threadIdx.x; k < KIN; k += blockDim.x) xi[k] = in[g * KIN + k];
    __syncthreads();
    int j = threadIdx.x;
    if (j < KOUT) {
        float s = b[j];
        for (int k = 0; k < KIN; k++) s = fmaf(xi[k], W[k * KOUT + j], s);
        if (RELU) s = fmaxf(s, 0.f);
        out[g * KOUT + j] = s;
    }
}

// ---------------- launch ----------------
extern "C" void kernel_launch(void* const* d_in, const int* in_sizes, int n_in,
                              void* d_out, int out_size, void* d_ws, size_t ws_size,
                              hipStream_t stream) {
    const float* x     = (const float*)d_in[0];
    const int*   ei    = (const int*)d_in[1];
    const int*   batch = (const int*)d_in[2];
    const float *W[5], *asrc[5], *adst[5], *bc[5];
    for (int i = 0; i < 5; i++) {
        W[i]    = (const float*)d_in[3 + i * 4];
        asrc[i] = (const float*)d_in[4 + i * 4];
        adst[i] = (const float*)d_in[5 + i * 4];
        bc[i]   = (const float*)d_in[6 + i * 4];
    }
    const float* lw1 = (const float*)d_in[23];
    const float* lb1 = (const float*)d_in[24];
    const float* lw2 = (const float*)d_in[25];
    const float* lb2 = (const float*)d_in[26];
    const float* lw3 = (const float*)d_in[27];
    const float* lb3 = (const float*)d_in[28];
    float* out = (float*)d_out;

    const int N  = in_sizes[0] / F_IN;
    const int E  = in_sizes[1] / 2;
    const int G  = out_size / 29;
    const int TE = E + N;
    const int* esrc = ei;
    const int* edst = ei + E;

    // workspace carve
    char* p = (char*)d_ws;
    auto carve = [&](size_t bytes) { void* r = (void*)p; p += ((bytes + 255) / 256) * 256; return r; };
    float*          hbuf = (float*)carve((size_t)N * HC * 4);          // GEMM out h (fp32)
    unsigned short* Ah   = (unsigned short*)carve((size_t)N * KP0 * 2);
    unsigned short* Al   = (unsigned short*)carve((size_t)N * KP0 * 2);
    float*          outF = (float*)Ah;  // aliases Ah/Al (dead by the time L5 gather writes)
    unsigned short* Wth  = (unsigned short*)carve((size_t)NPAD * KP0 * 2);
    unsigned short* Wtl  = (unsigned short*)carve((size_t)NPAD * KP0 * 2);
    float* es_     = (float*)carve((size_t)N * 2 * 4);
    float* ed_     = (float*)carve((size_t)N * 2 * 4);
    int*   deg     = (int*)carve((size_t)N * 4);
    int*   incl    = (int*)carve((size_t)N * 4);
    int*   bsums   = (int*)carve(SCAN_BS * 4);
    int*   row_ptr = (int*)carve((size_t)(N + 1) * 4);
    int*   cursor  = (int*)carve((size_t)N * 4);
    int*   col_src = (int*)carve((size_t)TE * 4);
    int*   gstart  = (int*)carve((size_t)(G + 1) * 4);
    float* pool    = (float*)carve((size_t)G * HC * 4);
    float* t1      = (float*)carve((size_t)G * 100 * 4);
    float* t2      = (float*)carve((size_t)G * 100 * 4);

    const int nBlkN   = (N + 255) / 256;
    const int nBlkE   = (E + 255) / 256;
    const int nBlkTE  = (TE + 255) / 256;
    const int nScanB  = (N + SCAN_BS - 1) / SCAN_BS;
    const int nWaveB  = (N + 3) / 4;
    const int nGemmB  = (N + 63) / 64;
    const int nPoolB  = (N + 63) / 64;

    // ---- CSR build ----
    init_deg<<<nBlkN, 256, 0, stream>>>(deg, N);
    count_deg<<<nBlkE, 256, 0, stream>>>(edst, deg, E);
    scan_block<<<nScanB, SCAN_BS, 0, stream>>>(deg, incl, bsums, N);
    scan_sums<<<1, SCAN_BS, 0, stream>>>(bsums, nScanB);
    scan_final<<<nScanB, SCAN_BS, 0, stream>>>(incl, deg, bsums, row_ptr, cursor, N);
    fill_csr<<<nBlkTE, 256, 0, stream>>>(esrc, edst, cursor, col_src, E, N);

    // ---- input split ----
    conv_x<<<(N * (KP0 / 4) + 255) / 256, 256, 0, stream>>>(x, Ah, Al, N);

    // ---- 5 GAT layers ----
    for (int L = 0; L < 5; L++) {
        int K  = (L == 0) ? F_IN : HC;
        int Kp = (L == 0) ? KP0 : KP1;
        conv_w<<<(NPAD * Kp + 255) / 256, 256, 0, stream>>>(W[L], Wth, Wtl, K, Kp);
        gemm_split<<<nGemmB, 256, 0, stream>>>(Ah, Al, Wth, Wtl, asrc[L], adst[L],
                                               hbuf, es_, ed_, N, Kp);
        if (L < 4)
            gat_gather<false, true><<<nWaveB, 256, 0, stream>>>(hbuf, es_, ed_, row_ptr, col_src,
                                                                bc[L], nullptr, Ah, Al, N);
        else
            gat_gather<true, false><<<nWaveB, 256, 0, stream>>>(hbuf, es_, ed_, row_ptr, col_src,
                                                                bc[L], outF, nullptr, nullptr, N);
    }

    // ---- pooling ----
    graph_bounds<<<nBlkN, 256, 0, stream>>>(batch, gstart, N, G);
    pool_zero<<<(G * HC + 255) / 256, 256, 0, stream>>>(pool, G * HC);
    pool_part<<<nPoolB, 256, 0, stream>>>(outF, batch, pool, N);
    pool_div<<<(G * HC + 255) / 256, 256, 0, stream>>>(pool, gstart, G);

    // ---- MLP head ----
    mlp<200, 100, true ><<<G, 128, 0, stream>>>(pool, lw1, lb1, t1);
    mlp<100, 100, true ><<<G, 128, 0, stream>>>(t1, lw2, lb2, t2);
    mlp<100, 29,  false><<<G, 128, 0, stream>>>(t2, lw3, lb3, out);
}

// Round 12
// 794.879 us; speedup vs baseline: 1.3040x; 1.0187x over previous
//
#include <hip/hip_runtime.h>
#include <hip/hip_bf16.h>
#include <math.h>

// ---------------- constants (from reference) ----------------
#define F_IN   336
#define HC     200      // H*C
#define Cch    100      // channels per head
#define SLOPE  0.2f
#define SCAN_BS 256

// padded dims for MFMA GEMM
#define NPAD   224      // HC padded to 14*16
#define KP0    352      // F_IN padded to mult of 32
#define KP1    224      // HC padded to mult of 32

using short8   = __attribute__((ext_vector_type(8))) short;
using float4v  = __attribute__((ext_vector_type(4))) float;
using ushort4v = __attribute__((ext_vector_type(4))) unsigned short;
using float2v  = __attribute__((ext_vector_type(2))) float;

// ---------------- bf16 split helpers ----------------
__device__ inline unsigned short rne_bf16(float v) {
    unsigned int u = __float_as_uint(v);
    return (unsigned short)((u + 0x7fffu + ((u >> 16) & 1u)) >> 16);
}
__device__ inline void split_bf(float v, unsigned short& hi, unsigned short& lo) {
    hi = rne_bf16(v);
    float hv = __uint_as_float(((unsigned int)hi) << 16);
    lo = rne_bf16(v - hv);
}

// ---------------- CSR build ----------------
__global__ void init_deg(int* deg, int n) {
    int i = blockIdx.x * 256 + threadIdx.x;
    if (i < n) deg[i] = 1;   // self-loop
}

__global__ void count_deg(const int* __restrict__ dst, int* deg, int e) {
    int i = blockIdx.x * 256 + threadIdx.x;
    if (i < e) atomicAdd(&deg[dst[i]], 1);
}

__global__ void scan_block(const int* __restrict__ deg, int* incl, int* bsums, int n) {
    __shared__ int sm[SCAN_BS];
    int i = blockIdx.x * SCAN_BS + threadIdx.x;
    int v = (i < n) ? deg[i] : 0;
    sm[threadIdx.x] = v;
    __syncthreads();
    for (int off = 1; off < SCAN_BS; off <<= 1) {
        int t = (threadIdx.x >= off) ? sm[threadIdx.x - off] : 0;
        __syncthreads();
        sm[threadIdx.x] += t;
        __syncthreads();
    }
    if (i < n) incl[i] = sm[threadIdx.x];
    if (threadIdx.x == SCAN_BS - 1) bsums[blockIdx.x] = sm[threadIdx.x];
}

__global__ void scan_sums(int* bsums, int nb) {
    __shared__ int sm[SCAN_BS];
    int v = (threadIdx.x < nb) ? bsums[threadIdx.x] : 0;
    sm[threadIdx.x] = v;
    __syncthreads();
    for (int off = 1; off < SCAN_BS; off <<= 1) {
        int t = (threadIdx.x >= off) ? sm[threadIdx.x - off] : 0;
        __syncthreads();
        sm[threadIdx.x] += t;
        __syncthreads();
    }
    if (threadIdx.x < nb) bsums[threadIdx.x] = sm[threadIdx.x] - v;  // exclusive
}

__global__ void scan_final(const int* __restrict__ incl, const int* __restrict__ deg,
                           const int* __restrict__ bsums, int* row_ptr, int* cursor, int n) {
    int i = blockIdx.x * SCAN_BS + threadIdx.x;
    if (i < n) {
        int inc = incl[i] + bsums[i / SCAN_BS];
        int ex  = inc - deg[i];
        row_ptr[i] = ex;
        cursor[i]  = ex;
        if (i == n - 1) row_ptr[n] = inc;
    }
}

__global__ void fill_csr(const int* __restrict__ src, const int* __restrict__ dst,
                         int* cursor, int* col_src, int e, int n) {
    int i = blockIdx.x * 256 + threadIdx.x;
    int te = e + n;
    if (i >= te) return;
    int s, d;
    if (i < e) { s = src[i]; d = dst[i]; }
    else       { s = i - e;  d = i - e; }
    int pos = atomicAdd(&cursor[d], 1);
    col_src[pos] = s;
}

// ---------------- split conversions ----------------
__global__ void conv_x(const float* __restrict__ x, unsigned short* __restrict__ Ah,
                       unsigned short* __restrict__ Al, int n_nodes) {
    const int GPR = KP0 / 4;   // 88 groups per row
    int i = blockIdx.x * 256 + threadIdx.x;
    int tot = n_nodes * GPR;
    if (i >= tot) return;
    int row = i / GPR, g4 = i - row * GPR;
    int col = g4 * 4;
    float4v v = {0.f, 0.f, 0.f, 0.f};
    if (col < F_IN) v = *(const float4v*)(x + (size_t)row * F_IN + col);
    ushort4v hv, lv;
    split_bf(v.x, ((unsigned short*)&hv)[0], ((unsigned short*)&lv)[0]);
    split_bf(v.y, ((unsigned short*)&hv)[1], ((unsigned short*)&lv)[1]);
    split_bf(v.z, ((unsigned short*)&hv)[2], ((unsigned short*)&lv)[2]);
    split_bf(v.w, ((unsigned short*)&hv)[3], ((unsigned short*)&lv)[3]);
    size_t b = (size_t)row * KP0 + col;
    *(ushort4v*)(Ah + b) = hv;
    *(ushort4v*)(Al + b) = lv;
}

// all 5 layers' weights split in ONE dispatch, layer-concatenated layout:
// [L0: NPAD*KP0][L1..L4: NPAD*KP1 each]   (R11: 5 dispatches -> 1)
__global__ void conv_w_all(const float* __restrict__ W0, const float* __restrict__ W1,
                           const float* __restrict__ W2, const float* __restrict__ W3,
                           const float* __restrict__ W4,
                           unsigned short* __restrict__ Bh, unsigned short* __restrict__ Bl) {
    const int SZ0 = NPAD * KP0, SZ = NPAD * KP1;
    const int TOT = SZ0 + 4 * SZ;
    int i = blockIdx.x * 256 + threadIdx.x;
    if (i >= TOT) return;
    const float* W; int Kp, K, idx;
    if (i < SZ0) { W = W0; Kp = KP0; K = F_IN; idx = i; }
    else {
        int j = i - SZ0; int l = j / SZ; idx = j - l * SZ;
        W = (l == 0) ? W1 : (l == 1) ? W2 : (l == 2) ? W3 : W4;
        Kp = KP1; K = HC;
    }
    int n = idx / Kp, k = idx - n * Kp;
    float v = (n < HC && k < K) ? W[(size_t)k * HC + n] : 0.f;
    unsigned short hi, lo;
    split_bf(v, hi, lo);
    Bh[i] = hi; Bl[i] = lo;
}

// ---------------- split-bf16 MFMA GEMM + fused attention scores ----------------
// h[M,200] = A[M,Kp] @ Wt^T ; es/ed[n][head] = sum_c h[n][c]*a{s,d}[c]
// R8/R9 lesson: direct-to-reg and small-block variants both land at the same
// ~10% MfmaUtil plateau but slower overall; this LDS-staged 64x224 block is
// the empirical best. Do not re-speculate without new counter evidence.
#define LDK 40   // LDS k-stride (32 + 8 pad -> 2-way bank conflicts only, free per m136)
__global__ __launch_bounds__(256, 2) void gemm_split(
    const unsigned short* __restrict__ Ah, const unsigned short* __restrict__ Al,
    const unsigned short* __restrict__ Bh, const unsigned short* __restrict__ Bl,
    const float* __restrict__ asrc, const float* __restrict__ adst,
    float* __restrict__ h, float* __restrict__ es, float* __restrict__ ed,
    int M, int Kp)
{
    __shared__ unsigned short As[2][64][LDK];
    __shared__ unsigned short Bs[2][NPAD][LDK];
    __shared__ float sc[64][4];    // es0, es1, ed0, ed1 per block row
    int tid  = threadIdx.x;
    int wave = tid >> 6, lane = tid & 63;
    int quad = lane >> 4, l16 = lane & 15;
    int wm = (wave >> 1) * 32;
    int wn = (wave & 1) * 112;
    int r0 = blockIdx.x * 64;

    ((float*)sc)[tid] = 0.f;   // 64*4 == 256 — one element per thread

    float4v acc[2][7];
#pragma unroll
    for (int mt = 0; mt < 2; mt++)
#pragma unroll
        for (int nt = 0; nt < 7; nt++)
            acc[mt][nt] = (float4v){0.f, 0.f, 0.f, 0.f};

    for (int k0 = 0; k0 < Kp; k0 += 32) {
#pragma unroll
        for (int i = 0; i < 2; i++) {
            int c = tid + 256 * i;
            int s = c >> 8;
            int cc = c & 255;
            int row = cc >> 2, kc = (cc & 3) * 8;
            const unsigned short* g = s ? Al : Ah;
            uint4 v = make_uint4(0u, 0u, 0u, 0u);
            int gr = r0 + row;
            if (gr < M) v = *(const uint4*)(g + (size_t)gr * Kp + k0 + kc);
            *(uint4*)&As[s][row][kc] = v;
        }
#pragma unroll
        for (int i = 0; i < 7; i++) {
            int c = tid + 256 * i;
            int s = (c >= 896) ? 1 : 0;
            int cc = c - s * 896;
            int row = cc >> 2, kc = (cc & 3) * 8;
            const unsigned short* g = s ? Bl : Bh;
            *(uint4*)&Bs[s][row][kc] = *(const uint4*)(g + (size_t)row * Kp + k0 + kc);
        }
        __syncthreads();

        short8 a_h[2], a_l[2];
#pragma unroll
        for (int mt = 0; mt < 2; mt++) {
            a_h[mt] = *(const short8*)&As[0][wm + mt * 16 + l16][quad * 8];
            a_l[mt] = *(const short8*)&As[1][wm + mt * 16 + l16][quad * 8];
        }
#pragma unroll
        for (int nt = 0; nt < 7; nt++) {
            short8 b_h = *(const short8*)&Bs[0][wn + nt * 16 + l16][quad * 8];
            short8 b_l = *(const short8*)&Bs[1][wn + nt * 16 + l16][quad * 8];
#pragma unroll
            for (int mt = 0; mt < 2; mt++) {
                acc[mt][nt] = __builtin_amdgcn_mfma_f32_16x16x32_bf16(a_h[mt], b_h, acc[mt][nt], 0, 0, 0);
                acc[mt][nt] = __builtin_amdgcn_mfma_f32_16x16x32_bf16(a_h[mt], b_l, acc[mt][nt], 0, 0, 0);
                acc[mt][nt] = __builtin_amdgcn_mfma_f32_16x16x32_bf16(a_l[mt], b_h, acc[mt][nt], 0, 0, 0);
            }
        }
        __syncthreads();
    }

    // per-lane per-nt score weights (uniform loads, cached)
    float asc[7], adc[7];
    bool  vld[7];
    bool  hd1[7];
#pragma unroll
    for (int nt = 0; nt < 7; nt++) {
        int col = wn + nt * 16 + l16;
        vld[nt] = col < HC;
        hd1[nt] = col >= Cch;
        asc[nt] = vld[nt] ? asrc[col] : 0.f;
        adc[nt] = vld[nt] ? adst[col] : 0.f;
    }

    // epilogue: write h + accumulate score partials
#pragma unroll
    for (int mt = 0; mt < 2; mt++) {
        float p[4][4];
#pragma unroll
        for (int r = 0; r < 4; r++)
#pragma unroll
            for (int t = 0; t < 4; t++) p[r][t] = 0.f;
#pragma unroll
        for (int nt = 0; nt < 7; nt++) {
            int col = wn + nt * 16 + l16;
#pragma unroll
            for (int r = 0; r < 4; r++) {
                float v = acc[mt][nt][r];
                int grow = r0 + wm + mt * 16 + quad * 4 + r;
                if (vld[nt] && grow < M) h[(size_t)grow * HC + col] = v;
                float va = v * asc[nt], vd = v * adc[nt];
                p[r][0] += hd1[nt] ? 0.f : va;
                p[r][1] += hd1[nt] ? va  : 0.f;
                p[r][2] += hd1[nt] ? 0.f : vd;
                p[r][3] += hd1[nt] ? vd  : 0.f;
            }
        }
#pragma unroll
        for (int off = 1; off < 16; off <<= 1)
#pragma unroll
            for (int r = 0; r < 4; r++)
#pragma unroll
                for (int t = 0; t < 4; t++)
                    p[r][t] += __shfl_xor(p[r][t], off);
        if (l16 == 0) {
            int lrow = wm + mt * 16 + quad * 4;
#pragma unroll
            for (int r = 0; r < 4; r++)
#pragma unroll
                for (int t = 0; t < 4; t++)
                    atomicAdd(&sc[lrow + r][t], p[r][t]);
        }
    }
    __syncthreads();
    if (tid < 64) {
        int grow = r0 + tid;
        if (grow < M) {
            es[grow * 2 + 0] = sc[tid][0];
            es[grow * 2 + 1] = sc[tid][1];
            ed[grow * 2 + 0] = sc[tid][2];
            ed[grow * 2 + 1] = sc[tid][3];
        }
    }
}

// ---------------- fused softmax + weighted gather (wave per dst node) ----------------
// out = (sum_e p_e * h[src_e]) / (l + 1e-16) with p unnormalized. Pass A:
// wave-max of scores; pass B: p=exp(s-m), accumulate l, shfl-broadcast gather
// (R5 lesson: shfls in uniform control flow only).
template<bool WF, bool WB>
__global__ __launch_bounds__(256) void gat_gather(
    const float* __restrict__ h, const float* __restrict__ es, const float* __restrict__ ed,
    const int* __restrict__ row_ptr, const int* __restrict__ col_src,
    const float* __restrict__ bias, float* __restrict__ outF,
    unsigned short* __restrict__ oh, unsigned short* __restrict__ ol, int n_nodes)
{
    int wave = threadIdx.x >> 6, lane = threadIdx.x & 63;
    int n = blockIdx.x * 4 + wave;
    if (n >= n_nodes) return;
    int e0 = row_ptr[n], e1 = row_ptr[n + 1];
    bool act  = lane < 50;
    int  hsel = (lane >= 25) ? 1 : 0;
    float ed0 = ed[n * 2], ed1 = ed[n * 2 + 1];

    // ---- pass A: per-head max over incoming edges ----
    float m0 = -INFINITY, m1 = -INFINITY;
    for (int cbase = e0; cbase < e1; cbase += 64) {
        int cnt = e1 - cbase; if (cnt > 64) cnt = 64;
        if (lane < cnt) {
            int s = col_src[cbase + lane];
            float2v q = *(const float2v*)&es[s * 2];
            float s0 = q.x + ed0, s1 = q.y + ed1;
            s0 = s0 > 0.f ? s0 : SLOPE * s0;
            s1 = s1 > 0.f ? s1 : SLOPE * s1;
            m0 = fmaxf(m0, s0); m1 = fmaxf(m1, s1);
        }
    }
#pragma unroll
    for (int off = 1; off < 64; off <<= 1) {
        m0 = fmaxf(m0, __shfl_xor(m0, off));
        m1 = fmaxf(m1, __shfl_xor(m1, off));
    }

    // ---- pass B: p = exp(s-m), accumulate l, gather with unnormalized p ----
    float l0 = 0.f, l1 = 0.f;
    float4v a0 = {0.f, 0.f, 0.f, 0.f}, a1 = {0.f, 0.f, 0.f, 0.f};
    float4v a2 = {0.f, 0.f, 0.f, 0.f}, a3 = {0.f, 0.f, 0.f, 0.f};

    for (int cbase = e0; cbase < e1; cbase += 64) {
        int cnt = e1 - cbase; if (cnt > 64) cnt = 64;
        int   sidx = 0;
        float px = 0.f, py = 0.f;
        if (lane < cnt) {
            sidx = col_src[cbase + lane];
            float2v q = *(const float2v*)&es[sidx * 2];
            float s0 = q.x + ed0, s1 = q.y + ed1;
            s0 = s0 > 0.f ? s0 : SLOPE * s0;
            s1 = s1 > 0.f ? s1 : SLOPE * s1;
            px = __expf(s0 - m0);
            py = __expf(s1 - m1);
            l0 += px; l1 += py;
        }
        int j = 0;
        for (; j + 4 <= cnt; j += 4) {
            int s0 = __shfl(sidx, j + 0), s1 = __shfl(sidx, j + 1);
            int s2 = __shfl(sidx, j + 2), s3 = __shfl(sidx, j + 3);
            float x0 = __shfl(px, j + 0), y0 = __shfl(py, j + 0);
            float x1 = __shfl(px, j + 1), y1 = __shfl(py, j + 1);
            float x2 = __shfl(px, j + 2), y2 = __shfl(py, j + 2);
            float x3 = __shfl(px, j + 3), y3 = __shfl(py, j + 3);
            float p0 = hsel ? y0 : x0;
            float p1 = hsel ? y1 : x1;
            float p2 = hsel ? y2 : x2;
            float p3 = hsel ? y3 : x3;
            if (act) {
                float4v v0 = *(const float4v*)(h + (size_t)s0 * HC + lane * 4);
                float4v v1 = *(const float4v*)(h + (size_t)s1 * HC + lane * 4);
                float4v v2 = *(const float4v*)(h + (size_t)s2 * HC + lane * 4);
                float4v v3 = *(const float4v*)(h + (size_t)s3 * HC + lane * 4);
                a0.x += p0 * v0.x; a0.y += p0 * v0.y; a0.z += p0 * v0.z; a0.w += p0 * v0.w;
                a1.x += p1 * v1.x; a1.y += p1 * v1.y; a1.z += p1 * v1.z; a1.w += p1 * v1.w;
                a2.x += p2 * v2.x; a2.y += p2 * v2.y; a2.z += p2 * v2.z; a2.w += p2 * v2.w;
                a3.x += p3 * v3.x; a3.y += p3 * v3.y; a3.z += p3 * v3.z; a3.w += p3 * v3.w;
            }
        }
        for (; j < cnt; j++) {
            int s0 = __shfl(sidx, j);
            float x0 = __shfl(px, j), y0 = __shfl(py, j);
            float p0 = hsel ? y0 : x0;
            if (act) {
                float4v v0 = *(const float4v*)(h + (size_t)s0 * HC + lane * 4);
                a0.x += p0 * v0.x; a0.y += p0 * v0.y; a0.z += p0 * v0.z; a0.w += p0 * v0.w;
            }
        }
    }
#pragma unroll
    for (int off = 1; off < 64; off <<= 1) {
        l0 += __shfl_xor(l0, off);
        l1 += __shfl_xor(l1, off);
    }

    float4v acc;
    acc.x = (a0.x + a1.x) + (a2.x + a3.x);
    acc.y = (a0.y + a1.y) + (a2.y + a3.y);
    acc.z = (a0.z + a1.z) + (a2.z + a3.z);
    acc.w = (a0.w + a1.w) + (a2.w + a3.w);

    float li = 1.f / ((hsel ? l1 : l0) + 1e-16f);
    if (act) {
        float4v bb = *(const float4v*)(bias + lane * 4);
        float4v r;
        r.x = fmaxf(acc.x * li + bb.x, 0.f);
        r.y = fmaxf(acc.y * li + bb.y, 0.f);
        r.z = fmaxf(acc.z * li + bb.z, 0.f);
        r.w = fmaxf(acc.w * li + bb.w, 0.f);
        if (WF) {
            __builtin_nontemporal_store(r, (float4v*)(outF + (size_t)n * HC + lane * 4));
        }
        if (WB) {
            ushort4v hv, lv;
            split_bf(r.x, ((unsigned short*)&hv)[0], ((unsigned short*)&lv)[0]);
            split_bf(r.y, ((unsigned short*)&hv)[1], ((unsigned short*)&lv)[1]);
            split_bf(r.z, ((unsigned short*)&hv)[2], ((unsigned short*)&lv)[2]);
            split_bf(r.w, ((unsigned short*)&hv)[3], ((unsigned short*)&lv)[3]);
            size_t b = (size_t)n * NPAD + lane * 4;
            __builtin_nontemporal_store(hv, (ushort4v*)(oh + b));
            __builtin_nontemporal_store(lv, (ushort4v*)(ol + b));
        }
    } else if (WB && lane < 56) {   // zero pad cols 200..223
        ushort4v z = {0, 0, 0, 0};
        size_t b = (size_t)n * NPAD + lane * 4;
        __builtin_nontemporal_store(z, (ushort4v*)(oh + b));
        __builtin_nontemporal_store(z, (ushort4v*)(ol + b));
    }
}

// ---------------- pooling ----------------
// graph_bounds + pool_zero merged (independent index ranges, one grid) (R11)
__global__ void bounds_zero(const int* __restrict__ batch, int* gstart,
                            float* pool, int n, int g) {
    int i = blockIdx.x * 256 + threadIdx.x;
    if (i < g * HC) pool[i] = 0.f;
    if (i >= n) return;
    int b = batch[i];
    int bp = (i == 0) ? -1 : batch[i - 1];
    for (int q = bp + 1; q <= b; q++) gstart[q] = i;
    if (i == n - 1) for (int q = b + 1; q <= g; q++) gstart[q] = n;
}

__global__ __launch_bounds__(256) void pool_part(
    const float* __restrict__ x, const int* __restrict__ batch,
    float* __restrict__ pool, int n_nodes)
{
    int wave = threadIdx.x >> 6, lane = threadIdx.x & 63;
    int base = (blockIdx.x * 4 + wave) * 16;
    if (base >= n_nodes) return;
    bool act = lane < 50;
    int end = base + 16; if (end > n_nodes) end = n_nodes;
    float4v acc = {0.f, 0.f, 0.f, 0.f};
    int curg = batch[base];
    for (int n = base; n < end; n++) {
        int g = batch[n];
        if (g != curg) {
            if (act) {
                float* pp = pool + (size_t)curg * HC + lane * 4;
                atomicAdd(pp + 0, acc.x); atomicAdd(pp + 1, acc.y);
                atomicAdd(pp + 2, acc.z); atomicAdd(pp + 3, acc.w);
            }
            acc = (float4v){0.f, 0.f, 0.f, 0.f};
            curg = g;
        }
        if (act) {
            float4v v = *(const float4v*)(x + (size_t)n * HC + lane * 4);
            acc.x += v.x; acc.y += v.y; acc.z += v.z; acc.w += v.w;
        }
    }
    if (act) {
        float* pp = pool + (size_t)curg * HC + lane * 4;
        atomicAdd(pp + 0, acc.x); atomicAdd(pp + 1, acc.y);
        atomicAdd(pp + 2, acc.z); atomicAdd(pp + 3, acc.w);
    }
}

// ---------------- fused MLP head: pool-divide + 3 layers, one dispatch (R11) ----------------
__global__ __launch_bounds__(128) void mlp_head(
    const float* __restrict__ pool, const int* __restrict__ gstart,
    const float* __restrict__ lw1, const float* __restrict__ lb1,
    const float* __restrict__ lw2, const float* __restrict__ lb2,
    const float* __restrict__ lw3, const float* __restrict__ lb3,
    float* __restrict__ out)
{
    __shared__ float xa[200];
    __shared__ float xb[100];
    __shared__ float xc[100];
    int g = blockIdx.x, t = threadIdx.x;
    float inv = 1.f / fmaxf((float)(gstart[g + 1] - gstart[g]), 1.f);
    for (int k = t; k < 200; k += 128) xa[k] = pool[g * 200 + k] * inv;
    __syncthreads();
    if (t < 100) {
        float s = lb1[t];
        for (int k = 0; k < 200; k++) s = fmaf(xa[k], lw1[k * 100 + t], s);
        xb[t] = fmaxf(s, 0.f);
    }
    __syncthreads();
    if (t < 100) {
        float s = lb2[t];
        for (int k = 0; k < 100; k++) s = fmaf(xb[k], lw2[k * 100 + t], s);
        xc[t] = fmaxf(s, 0.f);
    }
    __syncthreads();
    if (t < 29) {
        float s = lb3[t];
        for (int k = 0; k < 100; k++) s = fmaf(xc[k], lw3[k * 29 + t], s);
        out[g * 29 + t] = s;
    }
}

// ---------------- launch ----------------
extern "C" void kernel_launch(void* const* d_in, const int* in_sizes, int n_in,
                              void* d_out, int out_size, void* d_ws, size_t ws_size,
                              hipStream_t stream) {
    const float* x     = (const float*)d_in[0];
    const int*   ei    = (const int*)d_in[1];
    const int*   batch = (const int*)d_in[2];
    const float *W[5], *asrc[5], *adst[5], *bc[5];
    for (int i = 0; i < 5; i++) {
        W[i]    = (const float*)d_in[3 + i * 4];
        asrc[i] = (const float*)d_in[4 + i * 4];
        adst[i] = (const float*)d_in[5 + i * 4];
        bc[i]   = (const float*)d_in[6 + i * 4];
    }
    const float* lw1 = (const float*)d_in[23];
    const float* lb1 = (const float*)d_in[24];
    const float* lw2 = (const float*)d_in[25];
    const float* lb2 = (const float*)d_in[26];
    const float* lw3 = (const float*)d_in[27];
    const float* lb3 = (const float*)d_in[28];
    float* out = (float*)d_out;

    const int N  = in_sizes[0] / F_IN;
    const int E  = in_sizes[1] / 2;
    const int G  = out_size / 29;
    const int TE = E + N;
    const int* esrc = ei;
    const int* edst = ei + E;

    const int WSZ0 = NPAD * KP0;          // layer-0 split-weight size
    const int WSZ  = NPAD * KP1;          // layers 1-4
    const int WTOT = WSZ0 + 4 * WSZ;

    // workspace carve
    char* p = (char*)d_ws;
    auto carve = [&](size_t bytes) { void* r = (void*)p; p += ((bytes + 255) / 256) * 256; return r; };
    float*          hbuf = (float*)carve((size_t)N * HC * 4);          // GEMM out h (fp32)
    unsigned short* Ah   = (unsigned short*)carve((size_t)N * KP0 * 2);
    unsigned short* Al   = (unsigned short*)carve((size_t)N * KP0 * 2);
    float*          outF = (float*)Ah;  // aliases Ah/Al (dead by the time L5 gather writes)
    unsigned short* Wth  = (unsigned short*)carve((size_t)WTOT * 2);
    unsigned short* Wtl  = (unsigned short*)carve((size_t)WTOT * 2);
    float* es_     = (float*)carve((size_t)N * 2 * 4);
    float* ed_     = (float*)carve((size_t)N * 2 * 4);
    int*   deg     = (int*)carve((size_t)N * 4);
    int*   incl    = (int*)carve((size_t)N * 4);
    int*   bsums   = (int*)carve(SCAN_BS * 4);
    int*   row_ptr = (int*)carve((size_t)(N + 1) * 4);
    int*   cursor  = (int*)carve((size_t)N * 4);
    int*   col_src = (int*)carve((size_t)TE * 4);
    int*   gstart  = (int*)carve((size_t)(G + 1) * 4);
    float* pool    = (float*)carve((size_t)G * HC * 4);

    const int nBlkN   = (N + 255) / 256;
    const int nBlkE   = (E + 255) / 256;
    const int nBlkTE  = (TE + 255) / 256;
    const int nScanB  = (N + SCAN_BS - 1) / SCAN_BS;
    const int nWaveB  = (N + 3) / 4;
    const int nGemmB  = (N + 63) / 64;
    const int nPoolB  = (N + 63) / 64;
    const int nBZ     = (((N > G * HC) ? N : G * HC) + 255) / 256;

    // ---- CSR build ----
    init_deg<<<nBlkN, 256, 0, stream>>>(deg, N);
    count_deg<<<nBlkE, 256, 0, stream>>>(edst, deg, E);
    scan_block<<<nScanB, SCAN_BS, 0, stream>>>(deg, incl, bsums, N);
    scan_sums<<<1, SCAN_BS, 0, stream>>>(bsums, nScanB);
    scan_final<<<nScanB, SCAN_BS, 0, stream>>>(incl, deg, bsums, row_ptr, cursor, N);
    fill_csr<<<nBlkTE, 256, 0, stream>>>(esrc, edst, cursor, col_src, E, N);

    // ---- input + weight splits (once) ----
    conv_x<<<(N * (KP0 / 4) + 255) / 256, 256, 0, stream>>>(x, Ah, Al, N);
    conv_w_all<<<(WTOT + 255) / 256, 256, 0, stream>>>(W[0], W[1], W[2], W[3], W[4], Wth, Wtl);

    // ---- 5 GAT layers ----
    for (int L = 0; L < 5; L++) {
        int Kp   = (L == 0) ? KP0 : KP1;
        int woff = (L == 0) ? 0 : WSZ0 + (L - 1) * WSZ;
        gemm_split<<<nGemmB, 256, 0, stream>>>(Ah, Al, Wth + woff, Wtl + woff,
                                               asrc[L], adst[L], hbuf, es_, ed_, N, Kp);
        if (L < 4)
            gat_gather<false, true><<<nWaveB, 256, 0, stream>>>(hbuf, es_, ed_, row_ptr, col_src,
                                                                bc[L], nullptr, Ah, Al, N);
        else
            gat_gather<true, false><<<nWaveB, 256, 0, stream>>>(hbuf, es_, ed_, row_ptr, col_src,
                                                                bc[L], outF, nullptr, nullptr, N);
    }

    // ---- pooling + MLP head ----
    bounds_zero<<<nBZ, 256, 0, stream>>>(batch, gstart, pool, N, G);
    pool_part<<<nPoolB, 256, 0, stream>>>(outF, batch, pool, N);
    mlp_head<<<G, 128, 0, stream>>>(pool, gstart, lw1, lb1, lw2, lb2, lw3, lb3, out);
}